// Round 1
// baseline (261.320 us; speedup 1.0000x reference)
//
#include <hip/hip_runtime.h>

#define N_NODES 100000
#define N_EDGES 1000000
#define IN_CH 128
#define HID_CH 64
#define N_CLS 40

#define NBUCK 782              // ceil(100000 / 128) buckets of 128 target cols

static inline int cdiv(int a, int b) { return (a + b - 1) / b; }

using bf16x8 = __attribute__((ext_vector_type(8))) short;   // 8 bf16 (4 VGPRs)
using f32x4  = __attribute__((ext_vector_type(4))) float;   // MFMA accumulator

// RNE float->bf16 pack (a in low 16, b in high 16)
__device__ __forceinline__ unsigned pack_bf2(float a, float b) {
    unsigned ua = __float_as_uint(a), ub = __float_as_uint(b);
    ua += 0x7fffu + ((ua >> 16) & 1u);
    ub += 0x7fffu + ((ub >> 16) & 1u);
    return (ua >> 16) | (ub & 0xffff0000u);
}
__device__ __forceinline__ unsigned short bf16_of(float a) {
    unsigned ua = __float_as_uint(a);
    ua += 0x7fffu + ((ua >> 16) & 1u);
    return (unsigned short)(ua >> 16);
}
__device__ __forceinline__ float bf_lo(unsigned u) { return __uint_as_float(u << 16); }
__device__ __forceinline__ float bf_hi(unsigned u) { return __uint_as_float(u & 0xffff0000u); }

// ---------------- bucket partition (col >> 7), pass 1: counts ----------------

__global__ __launch_bounds__(256)
void bucket_count_kernel(const int* __restrict__ cols, int* __restrict__ gcount, int E) {
    __shared__ int hist[NBUCK];
    for (int i = threadIdx.x; i < NBUCK; i += 256) hist[i] = 0;
    __syncthreads();
    int per = (E + gridDim.x - 1) / gridDim.x;
    int s = blockIdx.x * per;
    int e = min(E, s + per);
    for (int j = s + threadIdx.x; j < e; j += 256)
        atomicAdd(&hist[cols[j] >> 7], 1);
    __syncthreads();
    for (int i = threadIdx.x; i < NBUCK; i += 256)
        if (hist[i]) atomicAdd(&gcount[i], hist[i]);
}

// ---------------- scan 782 bucket counts -> boff[NBUCK+1], gcursor; offsets[N]=E ----------------

__global__ __launch_bounds__(1024)
void scan_bucket_kernel(const int* __restrict__ gcount, int* __restrict__ boff,
                        int* __restrict__ gcursor, int* __restrict__ offsets) {
    __shared__ int part[1024];
    int t = threadIdx.x;
    part[t] = (t < NBUCK) ? gcount[t] : 0;
    __syncthreads();
    for (int off = 1; off < 1024; off <<= 1) {
        int v = (t >= off) ? part[t - off] : 0;
        __syncthreads();
        part[t] += v;
        __syncthreads();
    }
    int excl = (t > 0) ? part[t - 1] : 0;
    if (t < NBUCK) { boff[t] = excl; gcursor[t] = excl; }
    if (t == NBUCK) { boff[NBUCK] = excl; offsets[N_NODES] = excl; }
}

// ---------------- pass 2: scatter edges into bucket order, packed (row<<7 | col&127) ----------------

__global__ __launch_bounds__(256)
void bucket_scatter_kernel(const int* __restrict__ rows, const int* __restrict__ cols,
                           int* __restrict__ gcursor, int* __restrict__ pedge, int E) {
    __shared__ int cur[NBUCK];
    for (int i = threadIdx.x; i < NBUCK; i += 256) cur[i] = 0;
    __syncthreads();
    int per = (E + gridDim.x - 1) / gridDim.x;
    int s = blockIdx.x * per;
    int e = min(E, s + per);
    for (int j = s + threadIdx.x; j < e; j += 256)
        atomicAdd(&cur[cols[j] >> 7], 1);
    __syncthreads();
    for (int i = threadIdx.x; i < NBUCK; i += 256) {
        int h = cur[i];
        cur[i] = h ? atomicAdd(&gcursor[i], h) : 0;
    }
    __syncthreads();
    for (int j = s + threadIdx.x; j < e; j += 256) {
        int c = cols[j];
        int pos = atomicAdd(&cur[c >> 7], 1);     // LDS returning atomic
        pedge[pos] = (rows[j] << 7) | (c & 127);
    }
}

// ---------------- per-bucket counting sort -> srow (CSR), offsets, dinv ----------------

__global__ __launch_bounds__(256)
void bucket_sort_kernel(const int* __restrict__ boff, const int* __restrict__ pedge,
                        int* __restrict__ srow, int* __restrict__ offsets,
                        float* __restrict__ dinv) {
    __shared__ int cnt[128];
    __shared__ int scn[128];
    __shared__ int cur[128];
    int b = blockIdx.x, t = threadIdx.x;
    if (t < 128) cnt[t] = 0;
    __syncthreads();
    int e0 = boff[b], e1 = boff[b + 1];
    for (int j = e0 + t; j < e1; j += 256)
        atomicAdd(&cnt[pedge[j] & 127], 1);
    __syncthreads();
    if (t < 128) scn[t] = cnt[t];
    __syncthreads();
    for (int off = 1; off < 128; off <<= 1) {
        int v = 0;
        if (t < 128 && t >= off) v = scn[t - off];
        __syncthreads();
        if (t < 128) scn[t] += v;
        __syncthreads();
    }
    if (t < 128) {
        int excl = (t > 0) ? scn[t - 1] : 0;
        cur[t] = excl;
        int node = b * 128 + t;
        if (node < N_NODES) {
            offsets[node] = e0 + excl;
            dinv[node] = cnt[t] ? rsqrtf((float)cnt[t]) : 0.f;
        }
    }
    __syncthreads();
    for (int j = e0 + t; j < e1; j += 256) {
        int p = pedge[j];
        int pos = atomicAdd(&cur[p & 127], 1);
        srow[e0 + pos] = p >> 7;
    }
}

// ---------------- MFMA fused GEMM ----------------
//  Y1b = bf16(dinv[r] * (X@W1))  (u16 stores, pull-gather input)
//  Y2  = X@W2 + Bias             (f32)
// 64-row tile / block of 256 (4 waves); wave w owns rows w*16..+15.
// X and W cast to bf16 at staging; W staged TRANSPOSED (wt[c][k]) so the
// B-fragment is one b128. Row pad 8 bf16 -> dword stride 68/36 (mod 32 = 4):
// 2-way bank aliasing = free. mfma_f32_16x16x32_bf16, f32 accumulate.
// A-frag: a[j]=A[m][ks*32+q*8+j], m=lane&15, q=lane>>4; C/D: col=lane&15,
// row=q*4+reg (verified maps).

template<int K, int C1, int C2>
__launch_bounds__(256)
__global__ void gemm_mfma_fused_kernel(const float* __restrict__ X,
                                       const float* __restrict__ W1,
                                       const float* __restrict__ W2,
                                       const float* __restrict__ Bias,
                                       const float* __restrict__ dinv,
                                       unsigned short* __restrict__ Y1b, // bf16 [N][C1]
                                       float* __restrict__ Y2, int N) {
    constexpr int CT = C1 + C2;
    constexpr int NT = CT / 16;            // 16-col tiles: 8 (L1) / 5 (L2)
    constexpr int KS = K / 32;             // k-steps: 4 (L1) / 2 (L2)
    constexpr int KP = (K + 8) / 2;        // dwords per padded bf16 row (68 / 36)
    static_assert(CT % 16 == 0 && K % 32 == 0, "shape");
    static_assert(C1 % 4 == 0 && C2 % 4 == 0, "staging vec4");

    __shared__ unsigned xb[64 * KP];       // bf16 x tile [64][K+8]
    __shared__ unsigned wt[CT * KP];       // bf16 W^T    [CT][K+8]
    __shared__ float dloc[64];

    const int tid = threadIdx.x;
    const int wave = tid >> 6;
    const int lane = tid & 63;
    const int m = lane & 15;
    const int quad = lane >> 4;
    const int r0 = blockIdx.x * 64;

    // stage dinv for this block's rows
    if (tid < 64) {
        int gr = r0 + tid;
        dloc[tid] = (gr < N) ? dinv[gr] : 0.f;
    }

    // stage x -> bf16 (row-major, padded)
    constexpr int XIT = 64 * (K / 4);
    for (int i = tid; i < XIT; i += 256) {
        int rr = i / (K / 4);
        int k4 = i - rr * (K / 4);
        int gr = r0 + rr;
        float4 v = make_float4(0.f, 0.f, 0.f, 0.f);
        if (gr < N)
            v = *reinterpret_cast<const float4*>(&X[(size_t)gr * K + k4 * 4]);
        uint2 p;
        p.x = pack_bf2(v.x, v.y);
        p.y = pack_bf2(v.z, v.w);
        *reinterpret_cast<uint2*>(&xb[rr * KP + k4 * 2]) = p;
    }

    // stage W1|W2 -> bf16 transposed: wt[c][k], k-pairs packed per dword
    constexpr int WIT = (K / 2) * (CT / 4);
    for (int i = tid; i < WIT; i += 256) {
        int kp = i / (CT / 4);
        int c4 = i - kp * (CT / 4);
        int k = kp * 2;
        int c = c4 * 4;
        float4 va, vb;
        if (c < C1) {
            va = *reinterpret_cast<const float4*>(&W1[(size_t)k * C1 + c]);
            vb = *reinterpret_cast<const float4*>(&W1[(size_t)(k + 1) * C1 + c]);
        } else {
            va = *reinterpret_cast<const float4*>(&W2[(size_t)k * C2 + (c - C1)]);
            vb = *reinterpret_cast<const float4*>(&W2[(size_t)(k + 1) * C2 + (c - C1)]);
        }
        wt[(c + 0) * KP + kp] = pack_bf2(va.x, vb.x);
        wt[(c + 1) * KP + kp] = pack_bf2(va.y, vb.y);
        wt[(c + 2) * KP + kp] = pack_bf2(va.z, vb.z);
        wt[(c + 3) * KP + kp] = pack_bf2(va.w, vb.w);
    }
    __syncthreads();

    // compute: wave strip = 16 rows, NT 16-col tiles, K in 32-steps
    const int rowbase = wave * 16;
    f32x4 acc[NT];
#pragma unroll
    for (int t = 0; t < NT; ++t) acc[t] = (f32x4){0.f, 0.f, 0.f, 0.f};

#pragma unroll
    for (int ks = 0; ks < KS; ++ks) {
        bf16x8 a = *reinterpret_cast<const bf16x8*>(&xb[(rowbase + m) * KP + ks * 16 + quad * 4]);
#pragma unroll
        for (int t = 0; t < NT; ++t) {
            bf16x8 b = *reinterpret_cast<const bf16x8*>(&wt[(t * 16 + m) * KP + ks * 16 + quad * 4]);
            acc[t] = __builtin_amdgcn_mfma_f32_16x16x32_bf16(a, b, acc[t], 0, 0, 0);
        }
    }

    // epilogue: D[q*4+reg][lane&15] per tile
#pragma unroll
    for (int t = 0; t < NT; ++t) {
        int c = t * 16 + m;
        float bias = (c >= C1) ? Bias[c - C1] : 0.f;
#pragma unroll
        for (int reg = 0; reg < 4; ++reg) {
            int rl = rowbase + quad * 4 + reg;
            int r = r0 + rl;
            if (r >= N) continue;
            float v = acc[t][reg];
            if (c < C1) {
                Y1b[(size_t)r * C1 + c] = bf16_of(v * dloc[rl]);
            } else {
                Y2[(size_t)r * C2 + (c - C1)] = v + bias;
            }
        }
    }
}

// ---------------- pull aggregation over pre-scaled bf16 H ----------------
//  Y[node] = relu(Y[node] + dinv[node] * sum_e H[srow[e]])
// Edge loop unrolled x4 (MLP=4; latency-bound, round-8/9 lesson).

template<int C>
__launch_bounds__(256)
__global__ void pull_bf16_kernel(const int* __restrict__ offsets,
                                 const int* __restrict__ srow,
                                 const float* __restrict__ dinv,
                                 const unsigned* __restrict__ H,   // bf16 [N][C], pre-scaled
                                 float* __restrict__ Y, int N) {
    constexpr int TPE = C / 4;             // lanes per node, 4 bf16 (uint2) each
    constexpr int CH = C / 2;              // uints per row
    int gid = blockIdx.x * blockDim.x + threadIdx.x;
    int node = gid / TPE;
    int lane = gid - node * TPE;
    if (node >= N) return;

    int e0 = offsets[node];
    int e1 = offsets[node + 1];
    float dc = dinv[node];

    float4 acc = make_float4(0.f, 0.f, 0.f, 0.f);
    int j = e0;
    for (; j + 4 <= e1; j += 4) {
        int r0 = srow[j + 0];
        int r1 = srow[j + 1];
        int r2 = srow[j + 2];
        int r3 = srow[j + 3];
        uint2 u0 = *reinterpret_cast<const uint2*>(&H[(size_t)r0 * CH + lane * 2]);
        uint2 u1 = *reinterpret_cast<const uint2*>(&H[(size_t)r1 * CH + lane * 2]);
        uint2 u2 = *reinterpret_cast<const uint2*>(&H[(size_t)r2 * CH + lane * 2]);
        uint2 u3 = *reinterpret_cast<const uint2*>(&H[(size_t)r3 * CH + lane * 2]);
        acc.x += (bf_lo(u0.x) + bf_lo(u1.x)) + (bf_lo(u2.x) + bf_lo(u3.x));
        acc.y += (bf_hi(u0.x) + bf_hi(u1.x)) + (bf_hi(u2.x) + bf_hi(u3.x));
        acc.z += (bf_lo(u0.y) + bf_lo(u1.y)) + (bf_lo(u2.y) + bf_lo(u3.y));
        acc.w += (bf_hi(u0.y) + bf_hi(u1.y)) + (bf_hi(u2.y) + bf_hi(u3.y));
    }
    for (; j < e1; ++j) {
        int r = srow[j];
        uint2 u = *reinterpret_cast<const uint2*>(&H[(size_t)r * CH + lane * 2]);
        acc.x += bf_lo(u.x);
        acc.y += bf_hi(u.x);
        acc.z += bf_lo(u.y);
        acc.w += bf_hi(u.y);
    }

    float4* Y4 = reinterpret_cast<float4*>(Y);
    size_t yi = (size_t)node * TPE + lane;
    float4 y = Y4[yi];
    y.x = fmaxf(fmaf(dc, acc.x, y.x), 0.f);
    y.y = fmaxf(fmaf(dc, acc.y, y.y), 0.f);
    y.z = fmaxf(fmaf(dc, acc.z, y.z), 0.f);
    y.w = fmaxf(fmaf(dc, acc.w, y.w), 0.f);
    Y4[yi] = y;
}

// ---------------- launcher ----------------

extern "C" void kernel_launch(void* const* d_in, const int* in_sizes, int n_in,
                              void* d_out, int out_size, void* d_ws, size_t ws_size,
                              hipStream_t stream) {
    const float* x       = (const float*)d_in[0];
    const int*   eidx    = (const int*)d_in[1];
    const float* w1_init = (const float*)d_in[2];
    const float* w1_root = (const float*)d_in[3];
    const float* b1      = (const float*)d_in[4];
    const float* w2_init = (const float*)d_in[5];
    const float* w2_root = (const float*)d_in[6];
    const float* b2      = (const float*)d_in[7];
    float* out = (float*)d_out;

    const int* rows = eidx;                // edge_index[0] (source)
    const int* cols = eidx + N_EDGES;      // edge_index[1] (target)

    // workspace layout (4-byte units)
    int* wsi = (int*)d_ws;
    int*      gcount  = wsi;                         //     784
    int*      boff    = wsi + 784;                   //     788 (NBUCK+1 = 783 used)
    int*      gcursor = wsi + 1572;                  //     788
    float*    dinv    = (float*)(wsi + 2360);        //   100,000
    int*      offsets = wsi + 102360;                //   100,004 (N_NODES+1 used)
    int*      srow    = wsi + 202364;                // 1,000,000
    unsigned* h0b     = (unsigned*)(wsi + 1202364);  // 3,200,000 uints (bf16 h, reused as h2b)
    int*      pedge   = wsi + 1202364;               // aliases h0b: dead before gemm L1
    float*    agg1    = (float*)(wsi + 4402364);     // 6,400,000
    unsigned* h2b     = h0b;
    // total 10,802,364 * 4 B = 43.2 MB

    // ---- graph prep: bucket partition -> sorted CSR + dinv (no global per-edge atomics) ----
    hipMemsetAsync(gcount, 0, 784 * sizeof(int), stream);
    bucket_count_kernel<<<128, 256, 0, stream>>>(cols, gcount, N_EDGES);
    scan_bucket_kernel<<<1, 1024, 0, stream>>>(gcount, boff, gcursor, offsets);
    bucket_scatter_kernel<<<128, 256, 0, stream>>>(rows, cols, gcursor, pedge, N_EDGES);
    bucket_sort_kernel<<<NBUCK, 256, 0, stream>>>(boff, pedge, srow, offsets, dinv);

    const int GGRID = cdiv(N_NODES, 64);   // 1563

    // ---- layer 1 ----
    gemm_mfma_fused_kernel<IN_CH, HID_CH, HID_CH><<<GGRID, 256, 0, stream>>>(
        x, w1_init, w1_root, b1, dinv, (unsigned short*)h0b, agg1, N_NODES);
    pull_bf16_kernel<HID_CH><<<cdiv(N_NODES * (HID_CH / 4), 256), 256, 0, stream>>>(
        offsets, srow, dinv, h0b, agg1, N_NODES);

    // ---- layer 2 ----
    gemm_mfma_fused_kernel<HID_CH, N_CLS, N_CLS><<<GGRID, 256, 0, stream>>>(
        agg1, w2_init, w2_root, b2, dinv, (unsigned short*)h2b, out, N_NODES);
    pull_bf16_kernel<N_CLS><<<cdiv(N_NODES * (N_CLS / 4), 256), 256, 0, stream>>>(
        offsets, srow, dinv, h2b, out, N_NODES);
}